// Round 5
// baseline (218.411 us; speedup 1.0000x reference)
//
#include <hip/hip_runtime.h>
#include <hip/hip_bf16.h>

// Problem constants
#define BATCH  8
#define SEQ    2048
#define DMODEL 1024
#define DHEAD  128

typedef __attribute__((ext_vector_type(4))) float f32x4;
typedef __attribute__((ext_vector_type(4))) float f4;
typedef _Float16 f16;
typedef __attribute__((ext_vector_type(8))) _Float16 f16x8;
typedef __attribute__((ext_vector_type(8))) __bf16 bf16x8;

__device__ __forceinline__ unsigned short f2bf(float f) {
    unsigned u = __builtin_bit_cast(unsigned, f);
    u += 0x7fffu + ((u >> 16) & 1u);   // round-to-nearest-even
    return (unsigned short)(u >> 16);
}

#if __has_builtin(__builtin_amdgcn_exp2f)
#define EXP2(x) __builtin_amdgcn_exp2f(x)
#else
#define EXP2(x) exp2f(x)
#endif

__device__ __forceinline__ float fast_rcp(float x) {
#if __has_builtin(__builtin_amdgcn_rcpf)
    return __builtin_amdgcn_rcpf(x);
#else
    return 1.0f / x;
#endif
}

// ---------------------------------------------------------------------------
// Kernel 1: projections. Q,K in split-f16 (f32-grade, 3 MFMAs: scores need
// absolute precision ~0.01 because tanh transition lives at |s|~3 while raw
// scores have std ~1024). V in single-f16 MFMA -> bf16 store (output-grade;
// bf16 chosen for RANGE since P in [8.8e-27,1] pairs with V in one MFMA).
// BM=64, BN=128, BK=32, 4 waves.
// ---------------------------------------------------------------------------
__global__ __launch_bounds__(256) void proj_kernel(
    const float* __restrict__ x, const float* __restrict__ WQ,
    const float* __restrict__ WK, const float* __restrict__ WV,
    f16* __restrict__ Qh, f16* __restrict__ Ql,
    f16* __restrict__ Kh, f16* __restrict__ Kl,
    unsigned short* __restrict__ Vtb)
{
    // stride 40 f16 = 80B: 16B-aligned rows
    __shared__ f16 Ah[64][40],  Al[64][40];
    __shared__ f16 Bh[128][40], Bl[128][40];

    const int tid  = threadIdx.x;
    const int lane = tid & 63;
    const int w    = tid >> 6;
    const int lo   = lane & 15;
    const int hi   = lane >> 4;
    const int m0   = blockIdx.x * 64;
    const int mat  = blockIdx.y;               // 0=Q 1=K 2=V
    const float* W = (mat == 0) ? WQ : (mat == 1) ? WK : WV;
    const bool split = (mat < 2);

    f32x4 acc[8] = {};

    const int arow = tid >> 2;        // 0..63
    const int acol = (tid & 3) * 8;   // 0,8,16,24
    const int brow = tid >> 1;        // 0..127
    const int bcol = (tid & 1) * 16;  // 0,16

    for (int k0 = 0; k0 < DMODEL; k0 += 32) {
        __syncthreads();
        {   // stage x tile -> hi (and lo if split)
            const float* src = x + (size_t)(m0 + arow) * DMODEL + k0 + acol;
            f4 v0 = *(const f4*)(src);
            f4 v1 = *(const f4*)(src + 4);
            f16x8 oh, ol;
            #pragma unroll
            for (int j = 0; j < 4; ++j) {
                f16 h0 = (f16)v0[j]; oh[j]     = h0; ol[j]     = (f16)(v0[j] - (float)h0);
                f16 h1 = (f16)v1[j]; oh[j + 4] = h1; ol[j + 4] = (f16)(v1[j] - (float)h1);
            }
            *reinterpret_cast<f16x8*>(&Ah[arow][acol]) = oh;
            if (split) *reinterpret_cast<f16x8*>(&Al[arow][acol]) = ol;
        }
        {   // stage W tile -> hi (and lo if split)
            const float* src = W + (size_t)brow * DMODEL + k0 + bcol;
            #pragma unroll
            for (int halfc = 0; halfc < 2; ++halfc) {
                f4 v0 = *(const f4*)(src + halfc * 8);
                f4 v1 = *(const f4*)(src + halfc * 8 + 4);
                f16x8 oh, ol;
                #pragma unroll
                for (int j = 0; j < 4; ++j) {
                    f16 h0 = (f16)v0[j]; oh[j]     = h0; ol[j]     = (f16)(v0[j] - (float)h0);
                    f16 h1 = (f16)v1[j]; oh[j + 4] = h1; ol[j + 4] = (f16)(v1[j] - (float)h1);
                }
                *reinterpret_cast<f16x8*>(&Bh[brow][bcol + halfc * 8]) = oh;
                if (split) *reinterpret_cast<f16x8*>(&Bl[brow][bcol + halfc * 8]) = ol;
            }
        }
        __syncthreads();
        f16x8 ah = *reinterpret_cast<const f16x8*>(&Ah[w * 16 + lo][hi * 8]);
        if (split) {
            f16x8 al = *reinterpret_cast<const f16x8*>(&Al[w * 16 + lo][hi * 8]);
            #pragma unroll
            for (int nt = 0; nt < 8; ++nt) {
                f16x8 bh = *reinterpret_cast<const f16x8*>(&Bh[nt * 16 + lo][hi * 8]);
                f16x8 bl = *reinterpret_cast<const f16x8*>(&Bl[nt * 16 + lo][hi * 8]);
                acc[nt] = __builtin_amdgcn_mfma_f32_16x16x32_f16(ah, bh, acc[nt], 0, 0, 0);
                acc[nt] = __builtin_amdgcn_mfma_f32_16x16x32_f16(ah, bl, acc[nt], 0, 0, 0);
                acc[nt] = __builtin_amdgcn_mfma_f32_16x16x32_f16(al, bh, acc[nt], 0, 0, 0);
            }
        } else {
            #pragma unroll
            for (int nt = 0; nt < 8; ++nt) {
                f16x8 bh = *reinterpret_cast<const f16x8*>(&Bh[nt * 16 + lo][hi * 8]);
                acc[nt] = __builtin_amdgcn_mfma_f32_16x16x32_f16(ah, bh, acc[nt], 0, 0, 0);
            }
        }
    }

    // epilogue: D layout col = lane&15, row = (lane>>4)*4 + r
    const int rbase = w * 16 + hi * 4;
    if (mat < 2) {
        f16* dh = (mat == 0) ? Qh : Kh;
        f16* dl = (mat == 0) ? Ql : Kl;
        #pragma unroll
        for (int nt = 0; nt < 8; ++nt)
            #pragma unroll
            for (int r = 0; r < 4; ++r) {
                int m = m0 + rbase + r;
                int n = nt * 16 + lo;
                float v = acc[nt][r];
                f16 h = (f16)v;
                dh[(size_t)m * DHEAD + n] = h;
                dl[(size_t)m * DHEAD + n] = (f16)(v - (float)h);
            }
    } else {
        #pragma unroll
        for (int nt = 0; nt < 8; ++nt)
            #pragma unroll
            for (int r = 0; r < 4; ++r) {
                int m = m0 + rbase + r;
                int n = nt * 16 + lo;
                int bb = m >> 11, l = m & 2047;
                Vtb[((size_t)bb * DHEAD + n) * SEQ + l] = f2bf(acc[nt][r]);
            }
    }
}

// ---------------------------------------------------------------------------
// Kernel 2: causal tanh-capped attention, rescale-free flash.
// S_cap = 30*tanh(s) <= 30 -> fixed max 30:
//   P = exp(S_cap-30) = exp2(-86.5617 / (exp2(0.2551*s_raw) + 1)) in [8.8e-27,1]
// QK^T split-f16 (3 MFMAs); P,V bf16 (range). 8 waves share 16 q-rows,
// key tiles kt%8 across waves (linear: no online rescale). 3-level tree
// reduce at end. Balance: block does q-tile pair {p,127-p} -> uniform ~65
// iters/block. L2 locality: grid.x = batch so linear block id % 8 == batch
// -> all blocks of one batch land on one XCD (round-robin dispatch), K/V
// working set 1.5 MB -> L2-resident.
// ---------------------------------------------------------------------------
__global__ __launch_bounds__(512, 4) void attn_kernel(
    const f16* __restrict__ Qh, const f16* __restrict__ Ql,
    const f16* __restrict__ Kh, const f16* __restrict__ Kl,
    const unsigned short* __restrict__ Vtb, const int* __restrict__ mask,
    float* __restrict__ out)
{
    __shared__ unsigned short Plds[8][16][40];  // per-wave bf16 P tile, padded
    __shared__ float red[4][64][36];            // cross-wave reduction buffer

    const int tid  = threadIdx.x;
    const int lane = tid & 63;
    const int w    = tid >> 6;                  // 0..7
    const int lo   = lane & 15;
    const int hi   = lane >> 4;
    const int b    = blockIdx.x;                // batch -> XCD

    const float c2p = 0.25506061907448296f;   // (2*log2e)/sqrt(128)
    const float c1  = -86.561702453337804f;   // -60*log2e

    #pragma unroll 1
    for (int halfb = 0; halfb < 2; ++halfb) {
        const int qt  = halfb ? 127 - (int)blockIdx.y : (int)blockIdx.y;
        const int q0  = qt * 16;
        const int nkt = qt / 2 + 1;           // == q0/32 + 1

        // Q fragments (hi+lo) in registers for the whole tile
        f16x8 qh[4], ql[4];
        {
            const size_t off = ((size_t)(b * SEQ + q0 + lo)) * DHEAD + hi * 8;
            #pragma unroll
            for (int c = 0; c < 4; ++c) {
                qh[c] = *reinterpret_cast<const f16x8*>(Qh + off + c * 32);
                ql[c] = *reinterpret_cast<const f16x8*>(Ql + off + c * 32);
            }
        }

        f32x4 acc[8] = {};
        float rs[4] = {0.f, 0.f, 0.f, 0.f};

        for (int kt = w; kt < nkt; kt += 8) {
            const int k0 = kt * 32;

            // ---- early issue: V (consumed last), K both halves, masks ----
            bf16x8 vf[8];
            const unsigned short* vbase =
                Vtb + ((size_t)b * DHEAD + lo) * SEQ + k0 + hi * 8;
            #pragma unroll
            for (int dt = 0; dt < 8; ++dt)
                vf[dt] = *reinterpret_cast<const bf16x8*>(vbase + (size_t)dt * 16 * SEQ);

            f16x8 kh[2][4], kl[2][4];
            int mk[2];
            #pragma unroll
            for (int h = 0; h < 2; ++h) {
                const int key = k0 + h * 16 + lo;
                const size_t koff = ((size_t)(b * SEQ + key)) * DHEAD + hi * 8;
                #pragma unroll
                for (int c = 0; c < 4; ++c) {
                    kh[h][c] = *reinterpret_cast<const f16x8*>(Kh + koff + c * 32);
                    kl[h][c] = *reinterpret_cast<const f16x8*>(Kl + koff + c * 32);
                }
                mk[h] = mask[b * SEQ + key];
            }

            // ---- QK^T + softmax per 16-key half ----
            #pragma unroll
            for (int h = 0; h < 2; ++h) {
                f32x4 s = {};
                #pragma unroll
                for (int c = 0; c < 4; ++c) {
                    s = __builtin_amdgcn_mfma_f32_16x16x32_f16(qh[c], kh[h][c], s, 0, 0, 0);
                    s = __builtin_amdgcn_mfma_f32_16x16x32_f16(qh[c], kl[h][c], s, 0, 0, 0);
                    s = __builtin_amdgcn_mfma_f32_16x16x32_f16(ql[c], kh[h][c], s, 0, 0, 0);
                }
                const int key = k0 + h * 16 + lo;
                #pragma unroll
                for (int r = 0; r < 4; ++r) {
                    const int q = q0 + hi * 4 + r;
                    float t = EXP2(s[r] * c2p);               // e^{2s} (inf ok)
                    float p = EXP2(c1 * fast_rcp(t + 1.0f));
                    p = (key <= q && mk[h] != 0) ? p : 0.0f;  // causal + padding
                    rs[r] += p;
                    Plds[w][hi * 4 + r][h * 16 + lo] = f2bf(p);
                }
            }

            // P transpose via per-wave LDS (compiler inserts lgkmcnt)
            bf16x8 pa = *reinterpret_cast<const bf16x8*>(&Plds[w][lo][hi * 8]);
            #pragma unroll
            for (int dt = 0; dt < 8; ++dt)
                acc[dt] = __builtin_amdgcn_mfma_f32_16x16x32_bf16(pa, vf[dt], acc[dt], 0, 0, 0);
        }

        // ---- 3-level cross-wave tree reduction of acc + rs ----
        // level 1: waves 4..7 -> red[0..3], waves 0..3 add
        if (w >= 4) {
            float* dst = &red[w - 4][lane][0];
            #pragma unroll
            for (int dt = 0; dt < 8; ++dt)
                #pragma unroll
                for (int r = 0; r < 4; ++r) dst[dt * 4 + r] = acc[dt][r];
            #pragma unroll
            for (int r = 0; r < 4; ++r) dst[32 + r] = rs[r];
        }
        __syncthreads();
        if (w < 4) {
            const float* src = &red[w][lane][0];
            #pragma unroll
            for (int dt = 0; dt < 8; ++dt)
                #pragma unroll
                for (int r = 0; r < 4; ++r) acc[dt][r] += src[dt * 4 + r];
            #pragma unroll
            for (int r = 0; r < 4; ++r) rs[r] += src[32 + r];
        }
        __syncthreads();
        // level 2: waves 2..3 -> red[0..1], waves 0..1 add
        if (w >= 2 && w < 4) {
            float* dst = &red[w - 2][lane][0];
            #pragma unroll
            for (int dt = 0; dt < 8; ++dt)
                #pragma unroll
                for (int r = 0; r < 4; ++r) dst[dt * 4 + r] = acc[dt][r];
            #pragma unroll
            for (int r = 0; r < 4; ++r) dst[32 + r] = rs[r];
        }
        __syncthreads();
        if (w < 2) {
            const float* src = &red[w][lane][0];
            #pragma unroll
            for (int dt = 0; dt < 8; ++dt)
                #pragma unroll
                for (int r = 0; r < 4; ++r) acc[dt][r] += src[dt * 4 + r];
            #pragma unroll
            for (int r = 0; r < 4; ++r) rs[r] += src[32 + r];
        }
        __syncthreads();
        // level 3: wave 1 -> red[0], wave 0 adds + finalizes
        if (w == 1) {
            float* dst = &red[0][lane][0];
            #pragma unroll
            for (int dt = 0; dt < 8; ++dt)
                #pragma unroll
                for (int r = 0; r < 4; ++r) dst[dt * 4 + r] = acc[dt][r];
            #pragma unroll
            for (int r = 0; r < 4; ++r) dst[32 + r] = rs[r];
        }
        __syncthreads();
        if (w == 0) {
            const float* src = &red[0][lane][0];
            #pragma unroll
            for (int dt = 0; dt < 8; ++dt)
                #pragma unroll
                for (int r = 0; r < 4; ++r) acc[dt][r] += src[dt * 4 + r];
            #pragma unroll
            for (int r = 0; r < 4; ++r) {
                float v = rs[r] + src[32 + r];
                v += __shfl_xor(v, 1);
                v += __shfl_xor(v, 2);
                v += __shfl_xor(v, 4);
                v += __shfl_xor(v, 8);
                rs[r] = fast_rcp(v);
            }
            #pragma unroll
            for (int dt = 0; dt < 8; ++dt)
                #pragma unroll
                for (int r = 0; r < 4; ++r) {
                    size_t q = (size_t)q0 + hi * 4 + r;
                    out[((size_t)b * SEQ + q) * DHEAD + dt * 16 + lo] = acc[dt][r] * rs[r];
                }
        }
        __syncthreads();   // release red/Plds for the paired tile
    }
}

extern "C" void kernel_launch(void* const* d_in, const int* in_sizes, int n_in,
                              void* d_out, int out_size, void* d_ws, size_t ws_size,
                              hipStream_t stream) {
    const float* x   = (const float*)d_in[0];
    const int*   msk = (const int*)d_in[1];
    const float* WQ  = (const float*)d_in[2];
    const float* WK  = (const float*)d_in[3];
    const float* WV  = (const float*)d_in[4];
    float* out = (float*)d_out;

    // workspace: Qh|Ql|Kh|Kl (f16) | Vt (bf16), each B*L*128*2B = 4MB -> 20MB
    const size_t NE = (size_t)BATCH * SEQ * DHEAD;
    f16* Qh = (f16*)d_ws;
    f16* Ql = Qh + NE;
    f16* Kh = Ql + NE;
    f16* Kl = Kh + NE;
    unsigned short* Vtb = (unsigned short*)(Kl + NE);

    proj_kernel<<<dim3(BATCH * SEQ / 64, 3), 256, 0, stream>>>(x, WQ, WK, WV, Qh, Ql, Kh, Kl, Vtb);
    // grid.x = batch: linear block id % 8 == batch -> batch pinned to one XCD
    attn_kernel<<<dim3(BATCH, 64), 512, 0, stream>>>(Qh, Ql, Kh, Kl, Vtb, msk, out);
}

// Round 7
// 165.440 us; speedup vs baseline: 1.3202x; 1.3202x over previous
//
#include <hip/hip_runtime.h>
#include <hip/hip_bf16.h>

// Problem constants
#define BATCH  8
#define SEQ    2048
#define DMODEL 1024
#define DHEAD  128

typedef __attribute__((ext_vector_type(4))) float f32x4;
typedef __attribute__((ext_vector_type(4))) float f4;
typedef _Float16 f16;
typedef __attribute__((ext_vector_type(8))) _Float16 f16x8;
typedef __attribute__((ext_vector_type(8))) __bf16 bf16x8;
typedef __attribute__((ext_vector_type(16))) unsigned short u16x16;

__device__ __forceinline__ unsigned short f2bf(float f) {
    unsigned u = __builtin_bit_cast(unsigned, f);
    u += 0x7fffu + ((u >> 16) & 1u);   // round-to-nearest-even
    return (unsigned short)(u >> 16);
}

#if __has_builtin(__builtin_amdgcn_exp2f)
#define EXP2(x) __builtin_amdgcn_exp2f(x)
#else
#define EXP2(x) exp2f(x)
#endif

__device__ __forceinline__ float fast_rcp(float x) {
#if __has_builtin(__builtin_amdgcn_rcpf)
    return __builtin_amdgcn_rcpf(x);
#else
    return 1.0f / x;
#endif
}

// ---------------------------------------------------------------------------
// Kernel 1: FUSED projections (Q,K,V in one pass; x staged/split once).
// Q,K in split-f16 (f32-grade, 3 MFMAs each: scores need absolute precision
// ~0.01 because the tanh transition lives at |s|~3 while raw scores have
// std ~1024). V single-f16 MFMA -> bf16 store (output-grade; bf16 for RANGE:
// P in [8.8e-27,1] pairs with V in a bf16 MFMA). BM=64, BN=128, BK=32.
// ---------------------------------------------------------------------------
__global__ __launch_bounds__(256, 1) void proj_kernel(
    const float* __restrict__ x, const float* __restrict__ WQ,
    const float* __restrict__ WK, const float* __restrict__ WV,
    f16* __restrict__ Qh, f16* __restrict__ Ql,
    f16* __restrict__ Kh, f16* __restrict__ Kl,
    unsigned short* __restrict__ Vtb)
{
    __shared__ f16 Ah[64][40],  Al[64][40];      // x tile hi/lo
    __shared__ f16 BhQ[128][40], BlQ[128][40];   // W_Q tile hi/lo
    __shared__ f16 BhK[128][40], BlK[128][40];   // W_K tile hi/lo
    __shared__ f16 BhV[128][40];                 // W_V tile hi only

    const int tid  = threadIdx.x;
    const int lane = tid & 63;
    const int w    = tid >> 6;
    const int lo   = lane & 15;
    const int hi   = lane >> 4;
    const int m0   = blockIdx.x * 64;

    f32x4 accQ[8] = {}, accK[8] = {}, accV[8] = {};

    const int arow = tid >> 2;        // 0..63
    const int acol = (tid & 3) * 8;   // 0,8,16,24
    const int brow = tid >> 1;        // 0..127
    const int bcol = (tid & 1) * 16;  // 0,16

    for (int k0 = 0; k0 < DMODEL; k0 += 32) {
        __syncthreads();
        {   // stage x tile -> hi/lo (ONCE for all three mats)
            const float* src = x + (size_t)(m0 + arow) * DMODEL + k0 + acol;
            f4 v0 = *(const f4*)(src);
            f4 v1 = *(const f4*)(src + 4);
            f16x8 oh, ol;
            #pragma unroll
            for (int j = 0; j < 4; ++j) {
                f16 h0 = (f16)v0[j]; oh[j]     = h0; ol[j]     = (f16)(v0[j] - (float)h0);
                f16 h1 = (f16)v1[j]; oh[j + 4] = h1; ol[j + 4] = (f16)(v1[j] - (float)h1);
            }
            *reinterpret_cast<f16x8*>(&Ah[arow][acol]) = oh;
            *reinterpret_cast<f16x8*>(&Al[arow][acol]) = ol;
        }
        {   // stage W_Q, W_K (hi/lo) and W_V (hi)
            const size_t woff = (size_t)brow * DMODEL + k0 + bcol;
            #pragma unroll
            for (int halfc = 0; halfc < 2; ++halfc) {
                f4 q0v = *(const f4*)(WQ + woff + halfc * 8);
                f4 q1v = *(const f4*)(WQ + woff + halfc * 8 + 4);
                f4 k0v = *(const f4*)(WK + woff + halfc * 8);
                f4 k1v = *(const f4*)(WK + woff + halfc * 8 + 4);
                f4 v0v = *(const f4*)(WV + woff + halfc * 8);
                f4 v1v = *(const f4*)(WV + woff + halfc * 8 + 4);
                f16x8 qh8, ql8, kh8, kl8, vh8;
                #pragma unroll
                for (int j = 0; j < 4; ++j) {
                    f16 h;
                    h = (f16)q0v[j]; qh8[j]   = h; ql8[j]   = (f16)(q0v[j] - (float)h);
                    h = (f16)q1v[j]; qh8[j+4] = h; ql8[j+4] = (f16)(q1v[j] - (float)h);
                    h = (f16)k0v[j]; kh8[j]   = h; kl8[j]   = (f16)(k0v[j] - (float)h);
                    h = (f16)k1v[j]; kh8[j+4] = h; kl8[j+4] = (f16)(k1v[j] - (float)h);
                    vh8[j]   = (f16)v0v[j];
                    vh8[j+4] = (f16)v1v[j];
                }
                *reinterpret_cast<f16x8*>(&BhQ[brow][bcol + halfc * 8]) = qh8;
                *reinterpret_cast<f16x8*>(&BlQ[brow][bcol + halfc * 8]) = ql8;
                *reinterpret_cast<f16x8*>(&BhK[brow][bcol + halfc * 8]) = kh8;
                *reinterpret_cast<f16x8*>(&BlK[brow][bcol + halfc * 8]) = kl8;
                *reinterpret_cast<f16x8*>(&BhV[brow][bcol + halfc * 8]) = vh8;
            }
        }
        __syncthreads();
        f16x8 ah = *reinterpret_cast<const f16x8*>(&Ah[w * 16 + lo][hi * 8]);
        f16x8 al = *reinterpret_cast<const f16x8*>(&Al[w * 16 + lo][hi * 8]);
        #pragma unroll
        for (int nt = 0; nt < 8; ++nt) {
            f16x8 bh, bl;
            bh = *reinterpret_cast<const f16x8*>(&BhQ[nt * 16 + lo][hi * 8]);
            bl = *reinterpret_cast<const f16x8*>(&BlQ[nt * 16 + lo][hi * 8]);
            accQ[nt] = __builtin_amdgcn_mfma_f32_16x16x32_f16(ah, bh, accQ[nt], 0, 0, 0);
            accQ[nt] = __builtin_amdgcn_mfma_f32_16x16x32_f16(ah, bl, accQ[nt], 0, 0, 0);
            accQ[nt] = __builtin_amdgcn_mfma_f32_16x16x32_f16(al, bh, accQ[nt], 0, 0, 0);
            bh = *reinterpret_cast<const f16x8*>(&BhK[nt * 16 + lo][hi * 8]);
            bl = *reinterpret_cast<const f16x8*>(&BlK[nt * 16 + lo][hi * 8]);
            accK[nt] = __builtin_amdgcn_mfma_f32_16x16x32_f16(ah, bh, accK[nt], 0, 0, 0);
            accK[nt] = __builtin_amdgcn_mfma_f32_16x16x32_f16(ah, bl, accK[nt], 0, 0, 0);
            accK[nt] = __builtin_amdgcn_mfma_f32_16x16x32_f16(al, bh, accK[nt], 0, 0, 0);
            bh = *reinterpret_cast<const f16x8*>(&BhV[nt * 16 + lo][hi * 8]);
            accV[nt] = __builtin_amdgcn_mfma_f32_16x16x32_f16(ah, bh, accV[nt], 0, 0, 0);
        }
    }

    // epilogue: D layout col = lane&15, row = (lane>>4)*4 + r
    const int rbase = w * 16 + hi * 4;
    #pragma unroll
    for (int nt = 0; nt < 8; ++nt)
        #pragma unroll
        for (int r = 0; r < 4; ++r) {
            const int m = m0 + rbase + r;
            const int n = nt * 16 + lo;
            const size_t idx = (size_t)m * DHEAD + n;
            float vq = accQ[nt][r];
            f16 hq = (f16)vq;
            Qh[idx] = hq; Ql[idx] = (f16)(vq - (float)hq);
            float vk = accK[nt][r];
            f16 hk = (f16)vk;
            Kh[idx] = hk; Kl[idx] = (f16)(vk - (float)hk);
            const int bb = m >> 11, l = m & 2047;
            Vtb[((size_t)bb * DHEAD + n) * SEQ + l] = f2bf(accV[nt][r]);
        }
}

// ---------------------------------------------------------------------------
// Kernel 2: causal tanh-capped attention, rescale-free flash.
// S_cap = 30*tanh(s) <= 30 -> fixed max 30:
//   P = exp(S_cap-30) = exp2(-86.5617 / (exp2(0.2551*s_raw) + 1)) in [8.8e-27,1]
// QK^T split-f16 (3 MFMAs); P,V bf16 (range).
// Block = 4 waves x 16 DISTINCT q-rows (QBLK=64); all waves process the
// SAME key tile, staged in double-buffered LDS -> 4x intra-block K/V reuse.
// Reg-staged pipeline: issue next tile's global loads, compute current,
// ds_write, one barrier. No cross-wave reduction (waves own disjoint rows).
// K staging: 16 f16/thread (two f16x8) -> full 32x128 tile covered
// (r6 bug: 8/thread covered only cols 0..63 -> uninit LDS -> NaN).
// ---------------------------------------------------------------------------
__global__ __launch_bounds__(256) void attn_kernel(
    const f16* __restrict__ Qh, const f16* __restrict__ Ql,
    const f16* __restrict__ Kh, const f16* __restrict__ Kl,
    const unsigned short* __restrict__ Vtb, const int* __restrict__ mask,
    float* __restrict__ out)
{
    __shared__ f16 Khs[2][32][136];             // 17408 B
    __shared__ f16 Kls[2][32][136];             // 17408 B
    __shared__ unsigned short Vs[2][128][40];   // 20480 B
    __shared__ int Ms[2][32];                   //   256 B
    __shared__ unsigned short Plds[4][16][40];  //  5120 B  (total ~59 KB)

    const int tid  = threadIdx.x;
    const int lane = tid & 63;
    const int w    = tid >> 6;                  // 0..3
    const int lo   = lane & 15;
    const int hi   = lane >> 4;
    const int b    = blockIdx.x;
    const int qs   = blockIdx.y;                // 0..31
    const int q0   = qs * 64;
    const int nkt  = qs * 2 + 2;                // key tiles covering q0..q0+63
    const int qrow = q0 + w * 16;               // this wave's q-row base

    const float c2p = 0.25506061907448296f;   // (2*log2e)/sqrt(128)
    const float c1  = -86.561702453337804f;   // -60*log2e

    // Q fragments (hi+lo) in registers for the whole block
    f16x8 qh[4], ql[4];
    {
        const size_t off = ((size_t)(b * SEQ + qrow + lo)) * DHEAD + hi * 8;
        #pragma unroll
        for (int c = 0; c < 4; ++c) {
            qh[c] = *reinterpret_cast<const f16x8*>(Qh + off + c * 32);
            ql[c] = *reinterpret_cast<const f16x8*>(Ql + off + c * 32);
        }
    }

    // staging addresses (per thread): K tile 32x128 -> 16 f16/thread
    const int krow = tid >> 3;                  // 0..31
    const int kcol = (tid & 7) * 16;            // 0,16,...,112
    const int vrow = tid >> 1;                  // 0..127
    const int vcol = (tid & 1) * 16;            // 0,16

    f16x8  rKh0, rKh1, rKl0, rKl1;
    u16x16 rV;
    int    rM = 0;

    // prologue: load + write tile 0
    {
        const size_t koff = ((size_t)(b * SEQ + krow)) * DHEAD + kcol;
        rKh0 = *reinterpret_cast<const f16x8*>(Kh + koff);
        rKh1 = *reinterpret_cast<const f16x8*>(Kh + koff + 8);
        rKl0 = *reinterpret_cast<const f16x8*>(Kl + koff);
        rKl1 = *reinterpret_cast<const f16x8*>(Kl + koff + 8);
        rV   = *reinterpret_cast<const u16x16*>(Vtb + ((size_t)b * DHEAD + vrow) * SEQ + vcol);
        if (tid < 32) rM = mask[b * SEQ + tid];
        *reinterpret_cast<f16x8*>(&Khs[0][krow][kcol])     = rKh0;
        *reinterpret_cast<f16x8*>(&Khs[0][krow][kcol + 8]) = rKh1;
        *reinterpret_cast<f16x8*>(&Kls[0][krow][kcol])     = rKl0;
        *reinterpret_cast<f16x8*>(&Kls[0][krow][kcol + 8]) = rKl1;
        *reinterpret_cast<u16x16*>(&Vs[0][vrow][vcol]) = rV;
        if (tid < 32) Ms[0][tid] = rM;
    }
    __syncthreads();

    f32x4 acc[8] = {};
    float rs[4] = {0.f, 0.f, 0.f, 0.f};

    for (int kt = 0; kt < nkt; ++kt) {
        const int cur = kt & 1;
        const bool havenext = (kt + 1 < nkt);

        // issue next tile's global loads (latency hides under compute)
        if (havenext) {
            const int k0n = (kt + 1) * 32;
            const size_t koff = ((size_t)(b * SEQ + k0n + krow)) * DHEAD + kcol;
            rKh0 = *reinterpret_cast<const f16x8*>(Kh + koff);
            rKh1 = *reinterpret_cast<const f16x8*>(Kh + koff + 8);
            rKl0 = *reinterpret_cast<const f16x8*>(Kl + koff);
            rKl1 = *reinterpret_cast<const f16x8*>(Kl + koff + 8);
            rV   = *reinterpret_cast<const u16x16*>(Vtb + ((size_t)b * DHEAD + vrow) * SEQ + k0n + vcol);
            if (tid < 32) rM = mask[b * SEQ + k0n + tid];
        }

        // compute current tile (skip if fully causal-masked for this wave)
        if (kt * 32 <= qrow + 15) {
            const int k0 = kt * 32;
            #pragma unroll
            for (int h = 0; h < 2; ++h) {
                f32x4 s = {};
                #pragma unroll
                for (int c = 0; c < 4; ++c) {
                    f16x8 fkh = *reinterpret_cast<const f16x8*>(&Khs[cur][h * 16 + lo][c * 32 + hi * 8]);
                    f16x8 fkl = *reinterpret_cast<const f16x8*>(&Kls[cur][h * 16 + lo][c * 32 + hi * 8]);
                    s = __builtin_amdgcn_mfma_f32_16x16x32_f16(qh[c], fkh, s, 0, 0, 0);
                    s = __builtin_amdgcn_mfma_f32_16x16x32_f16(qh[c], fkl, s, 0, 0, 0);
                    s = __builtin_amdgcn_mfma_f32_16x16x32_f16(ql[c], fkh, s, 0, 0, 0);
                }
                const int key = k0 + h * 16 + lo;
                const int mk  = Ms[cur][h * 16 + lo];
                #pragma unroll
                for (int r = 0; r < 4; ++r) {
                    const int q = qrow + hi * 4 + r;
                    float t = EXP2(s[r] * c2p);               // e^{2s} (inf ok)
                    float p = EXP2(c1 * fast_rcp(t + 1.0f));
                    p = (key <= q && mk != 0) ? p : 0.0f;     // causal + padding
                    rs[r] += p;
                    Plds[w][hi * 4 + r][h * 16 + lo] = f2bf(p);
                }
            }
            // P transpose via per-wave LDS (compiler inserts lgkmcnt)
            bf16x8 pa = *reinterpret_cast<const bf16x8*>(&Plds[w][lo][hi * 8]);
            #pragma unroll
            for (int dt = 0; dt < 8; ++dt) {
                bf16x8 vf = *reinterpret_cast<const bf16x8*>(&Vs[cur][dt * 16 + lo][hi * 8]);
                acc[dt] = __builtin_amdgcn_mfma_f32_16x16x32_bf16(pa, vf, acc[dt], 0, 0, 0);
            }
        }

        // write next tile into the other buffer, then barrier
        if (havenext) {
            const int nxt = cur ^ 1;
            *reinterpret_cast<f16x8*>(&Khs[nxt][krow][kcol])     = rKh0;
            *reinterpret_cast<f16x8*>(&Khs[nxt][krow][kcol + 8]) = rKh1;
            *reinterpret_cast<f16x8*>(&Kls[nxt][krow][kcol])     = rKl0;
            *reinterpret_cast<f16x8*>(&Kls[nxt][krow][kcol + 8]) = rKl1;
            *reinterpret_cast<u16x16*>(&Vs[nxt][vrow][vcol]) = rV;
            if (tid < 32) Ms[nxt][tid] = rM;
        }
        __syncthreads();
    }

    // finalize: per-wave rs reduce over the 16 key-lanes of each hi-group
    float inv[4];
    #pragma unroll
    for (int r = 0; r < 4; ++r) {
        float v = rs[r];
        v += __shfl_xor(v, 1);
        v += __shfl_xor(v, 2);
        v += __shfl_xor(v, 4);
        v += __shfl_xor(v, 8);
        inv[r] = fast_rcp(v);
    }
    #pragma unroll
    for (int dt = 0; dt < 8; ++dt)
        #pragma unroll
        for (int r = 0; r < 4; ++r) {
            const size_t q = (size_t)qrow + hi * 4 + r;
            out[((size_t)b * SEQ + q) * DHEAD + dt * 16 + lo] = acc[dt][r] * inv[r];
        }
}

extern "C" void kernel_launch(void* const* d_in, const int* in_sizes, int n_in,
                              void* d_out, int out_size, void* d_ws, size_t ws_size,
                              hipStream_t stream) {
    const float* x   = (const float*)d_in[0];
    const int*   msk = (const int*)d_in[1];
    const float* WQ  = (const float*)d_in[2];
    const float* WK  = (const float*)d_in[3];
    const float* WV  = (const float*)d_in[4];
    float* out = (float*)d_out;

    // workspace: Qh|Ql|Kh|Kl (f16) | Vt (bf16), each B*L*128*2B = 4MB -> 20MB
    const size_t NE = (size_t)BATCH * SEQ * DHEAD;
    f16* Qh = (f16*)d_ws;
    f16* Ql = Qh + NE;
    f16* Kh = Ql + NE;
    f16* Kl = Kh + NE;
    unsigned short* Vtb = (unsigned short*)(Kl + NE);

    proj_kernel<<<dim3(BATCH * SEQ / 64), 256, 0, stream>>>(x, WQ, WK, WV, Qh, Ql, Kh, Kl, Vtb);
    attn_kernel<<<dim3(BATCH, SEQ / 64), 256, 0, stream>>>(Qh, Ql, Kh, Kl, Vtb, msk, out);
}

// Round 8
// 115.067 us; speedup vs baseline: 1.8981x; 1.4378x over previous
//
#include <hip/hip_runtime.h>
#include <hip/hip_bf16.h>

// Problem constants
#define BATCH  8
#define SEQ    2048
#define DMODEL 1024
#define DHEAD  128

typedef __attribute__((ext_vector_type(4))) float f32x4;
typedef __attribute__((ext_vector_type(4))) float f4;
typedef _Float16 f16;
typedef __attribute__((ext_vector_type(8))) _Float16 f16x8;
typedef __attribute__((ext_vector_type(8))) __bf16 bf16x8;
typedef __attribute__((ext_vector_type(16))) unsigned short u16x16;

__device__ __forceinline__ unsigned short f2bf(float f) {
    unsigned u = __builtin_bit_cast(unsigned, f);
    u += 0x7fffu + ((u >> 16) & 1u);   // round-to-nearest-even
    return (unsigned short)(u >> 16);
}

#if __has_builtin(__builtin_amdgcn_exp2f)
#define EXP2(x) __builtin_amdgcn_exp2f(x)
#else
#define EXP2(x) exp2f(x)
#endif

__device__ __forceinline__ float fast_rcp(float x) {
#if __has_builtin(__builtin_amdgcn_rcpf)
    return __builtin_amdgcn_rcpf(x);
#else
    return 1.0f / x;
#endif
}

// ---------------------------------------------------------------------------
// Kernel 1: FUSED projections, 8 waves (4m x 2n), reg-staged double-buffered
// LDS, ONE barrier per K-step. Q,K split-f16 (f32-grade scores: tanh
// transition at |s|~3 vs raw score std ~1024). V single-f16 -> bf16 store
// (range: P in [8.8e-27,1] pairs with V in a bf16 MFMA). BM=64, BN=128, BK=32.
// ---------------------------------------------------------------------------
__global__ __launch_bounds__(512) void proj_kernel(
    const float* __restrict__ x, const float* __restrict__ WQ,
    const float* __restrict__ WK, const float* __restrict__ WV,
    f16* __restrict__ Qh, f16* __restrict__ Ql,
    f16* __restrict__ Kh, f16* __restrict__ Kl,
    unsigned short* __restrict__ Vtb)
{
    __shared__ f16 Ah[2][64][40], Al[2][64][40];   // x tile hi/lo
    __shared__ f16 Bhs[2][3][128][40];             // W_Q, W_K, W_V hi
    __shared__ f16 Bls[2][2][128][40];             // W_Q, W_K lo

    const int tid  = threadIdx.x;
    const int lane = tid & 63;
    const int w    = tid >> 6;          // 0..7
    const int lo   = lane & 15;
    const int hi   = lane >> 4;
    const int wm   = w & 3;             // row quadrant (16 rows)
    const int wn   = w >> 2;            // col half (64 cols)
    const int m0   = blockIdx.x * 64;

    const int brow = tid >> 2;          // 0..127
    const int bcol = (tid & 3) * 8;     // 0,8,16,24
    const int arow = (tid & 255) >> 2;  // 0..63 (threads < 256)
    const int acol = (tid & 3) * 8;

    f32x4 accQ[4] = {}, accK[4] = {}, accV[4] = {};

    f4 rx0, rx1, rq0, rq1, rk0, rk1, rv0, rv1;

    auto load_regs = [&](int k0) {
        const size_t woff = (size_t)brow * DMODEL + k0 + bcol;
        rq0 = *(const f4*)(WQ + woff); rq1 = *(const f4*)(WQ + woff + 4);
        rk0 = *(const f4*)(WK + woff); rk1 = *(const f4*)(WK + woff + 4);
        rv0 = *(const f4*)(WV + woff); rv1 = *(const f4*)(WV + woff + 4);
        if (tid < 256) {
            const float* src = x + (size_t)(m0 + arow) * DMODEL + k0 + acol;
            rx0 = *(const f4*)src; rx1 = *(const f4*)(src + 4);
        }
    };
    auto split8 = [](f4 a, f4 b, f16x8& h8, f16x8& l8) {
        #pragma unroll
        for (int j = 0; j < 4; ++j) {
            f16 h = (f16)a[j]; h8[j]     = h; l8[j]     = (f16)(a[j] - (float)h);
            f16 g = (f16)b[j]; h8[j + 4] = g; l8[j + 4] = (f16)(b[j] - (float)g);
        }
    };
    auto conv_write = [&](int buf) {
        f16x8 h8, l8;
        split8(rq0, rq1, h8, l8);
        *reinterpret_cast<f16x8*>(&Bhs[buf][0][brow][bcol]) = h8;
        *reinterpret_cast<f16x8*>(&Bls[buf][0][brow][bcol]) = l8;
        split8(rk0, rk1, h8, l8);
        *reinterpret_cast<f16x8*>(&Bhs[buf][1][brow][bcol]) = h8;
        *reinterpret_cast<f16x8*>(&Bls[buf][1][brow][bcol]) = l8;
        #pragma unroll
        for (int j = 0; j < 4; ++j) { h8[j] = (f16)rv0[j]; h8[j + 4] = (f16)rv1[j]; }
        *reinterpret_cast<f16x8*>(&Bhs[buf][2][brow][bcol]) = h8;
        if (tid < 256) {
            split8(rx0, rx1, h8, l8);
            *reinterpret_cast<f16x8*>(&Ah[buf][arow][acol]) = h8;
            *reinterpret_cast<f16x8*>(&Al[buf][arow][acol]) = l8;
        }
    };

    load_regs(0);
    conv_write(0);
    __syncthreads();

    for (int ks = 0; ks < 32; ++ks) {
        const int cur = ks & 1;
        if (ks < 31) load_regs((ks + 1) * 32);

        f16x8 ah = *reinterpret_cast<const f16x8*>(&Ah[cur][wm * 16 + lo][hi * 8]);
        f16x8 al = *reinterpret_cast<const f16x8*>(&Al[cur][wm * 16 + lo][hi * 8]);
        #pragma unroll
        for (int nt = 0; nt < 4; ++nt) {
            const int row = wn * 64 + nt * 16 + lo;
            f16x8 bh = *reinterpret_cast<const f16x8*>(&Bhs[cur][0][row][hi * 8]);
            f16x8 bl = *reinterpret_cast<const f16x8*>(&Bls[cur][0][row][hi * 8]);
            accQ[nt] = __builtin_amdgcn_mfma_f32_16x16x32_f16(ah, bh, accQ[nt], 0, 0, 0);
            accQ[nt] = __builtin_amdgcn_mfma_f32_16x16x32_f16(ah, bl, accQ[nt], 0, 0, 0);
            accQ[nt] = __builtin_amdgcn_mfma_f32_16x16x32_f16(al, bh, accQ[nt], 0, 0, 0);
            bh = *reinterpret_cast<const f16x8*>(&Bhs[cur][1][row][hi * 8]);
            bl = *reinterpret_cast<const f16x8*>(&Bls[cur][1][row][hi * 8]);
            accK[nt] = __builtin_amdgcn_mfma_f32_16x16x32_f16(ah, bh, accK[nt], 0, 0, 0);
            accK[nt] = __builtin_amdgcn_mfma_f32_16x16x32_f16(ah, bl, accK[nt], 0, 0, 0);
            accK[nt] = __builtin_amdgcn_mfma_f32_16x16x32_f16(al, bh, accK[nt], 0, 0, 0);
            bh = *reinterpret_cast<const f16x8*>(&Bhs[cur][2][row][hi * 8]);
            accV[nt] = __builtin_amdgcn_mfma_f32_16x16x32_f16(ah, bh, accV[nt], 0, 0, 0);
        }
        if (ks < 31) conv_write(cur ^ 1);
        __syncthreads();
    }

    // epilogue: D layout col = lane&15, row = (lane>>4)*4 + r
    #pragma unroll
    for (int nt = 0; nt < 4; ++nt)
        #pragma unroll
        for (int r = 0; r < 4; ++r) {
            const int m = m0 + wm * 16 + hi * 4 + r;
            const int n = wn * 64 + nt * 16 + lo;
            const size_t idx = (size_t)m * DHEAD + n;
            float vq = accQ[nt][r];
            f16 hq = (f16)vq;
            Qh[idx] = hq; Ql[idx] = (f16)(vq - (float)hq);
            float vk = accK[nt][r];
            f16 hk = (f16)vk;
            Kh[idx] = hk; Kl[idx] = (f16)(vk - (float)hk);
            const int bb = m >> 11, l = m & 2047;
            Vtb[((size_t)bb * DHEAD + n) * SEQ + l] = f2bf(accV[nt][r]);
        }
}

// ---------------------------------------------------------------------------
// Kernel 2: causal tanh-capped attention, rescale-free flash.
// P = exp(30*tanh(s)-30) = exp2(-86.5617/(exp2(0.2551*s_raw)+1)) in [8.8e-27,1]
// 8 waves = (wq 0..3) x (wk 0..1): 64 q-rows per block, 64-key super-tile per
// iteration (wk picks the 32-key half). K hi/lo + V + mask staged once in
// double-buffered LDS (one barrier/iter, reg-staged) -> 4x K/V reuse.
// 2-way wk merge at the end through LDS (reuses K buffer). Heavy-first qs.
// ---------------------------------------------------------------------------
__global__ __launch_bounds__(512) void attn_kernel(
    const f16* __restrict__ Qh, const f16* __restrict__ Ql,
    const f16* __restrict__ Kh, const f16* __restrict__ Kl,
    const unsigned short* __restrict__ Vtb, const int* __restrict__ mask,
    float* __restrict__ out)
{
    __shared__ f16 Khs[2][64][136];             // 69632 B (both)
    __shared__ f16 Kls[2][64][136];
    __shared__ unsigned short Vs[2][128][72];   // 36864 B
    __shared__ int Ms[2][64];                   //   512 B
    __shared__ unsigned short Plds[8][16][40];  // 10240 B  (total ~117 KB)

    const int tid  = threadIdx.x;
    const int lane = tid & 63;
    const int w    = tid >> 6;                  // 0..7
    const int lo   = lane & 15;
    const int hi   = lane >> 4;
    const int wq   = w & 3;                     // q-row quadrant
    const int wk   = w >> 2;                    // key half
    const int b    = blockIdx.x;
    const int qs   = 31 - (int)blockIdx.y;      // heavy blocks first
    const int qrow = qs * 64 + wq * 16;
    const int niter = qs + 1;                   // 64-key super-tiles

    const float c2p = 0.25506061907448296f;     // (2*log2e)/sqrt(128)
    const float c1  = -86.561702453337804f;     // -60*log2e

    // Q fragments (hi+lo) in registers
    f16x8 qh[4], ql[4];
    {
        const size_t off = ((size_t)(b * SEQ + qrow + lo)) * DHEAD + hi * 8;
        #pragma unroll
        for (int c = 0; c < 4; ++c) {
            qh[c] = *reinterpret_cast<const f16x8*>(Qh + off + c * 32);
            ql[c] = *reinterpret_cast<const f16x8*>(Ql + off + c * 32);
        }
    }

    // staging maps: K 64x128 (16 f16/thread), V 128x64 (16 f16/thread)
    const int krow = tid >> 3;                  // 0..63
    const int kcol = (tid & 7) * 16;            // 0..112
    const int vrow = tid >> 2;                  // 0..127
    const int vcol = (tid & 3) * 16;            // 0,16,32,48

    f16x8  rKh0, rKh1, rKl0, rKl1;
    u16x16 rV;
    int    rM = 0;

    auto load_tile = [&](int kb) {
        const size_t koff = ((size_t)(b * SEQ + kb + krow)) * DHEAD + kcol;
        rKh0 = *reinterpret_cast<const f16x8*>(Kh + koff);
        rKh1 = *reinterpret_cast<const f16x8*>(Kh + koff + 8);
        rKl0 = *reinterpret_cast<const f16x8*>(Kl + koff);
        rKl1 = *reinterpret_cast<const f16x8*>(Kl + koff + 8);
        rV   = *reinterpret_cast<const u16x16*>(Vtb + ((size_t)b * DHEAD + vrow) * SEQ + kb + vcol);
        if (tid < 64) rM = mask[b * SEQ + kb + tid];
    };
    auto write_tile = [&](int buf) {
        *reinterpret_cast<f16x8*>(&Khs[buf][krow][kcol])     = rKh0;
        *reinterpret_cast<f16x8*>(&Khs[buf][krow][kcol + 8]) = rKh1;
        *reinterpret_cast<f16x8*>(&Kls[buf][krow][kcol])     = rKl0;
        *reinterpret_cast<f16x8*>(&Kls[buf][krow][kcol + 8]) = rKl1;
        *reinterpret_cast<u16x16*>(&Vs[buf][vrow][vcol]) = rV;
        if (tid < 64) Ms[buf][tid] = rM;
    };

    load_tile(0);
    write_tile(0);
    __syncthreads();

    f32x4 acc[8] = {};
    float rs[4] = {0.f, 0.f, 0.f, 0.f};

    for (int it = 0; it < niter; ++it) {
        const int cur = it & 1;
        if (it + 1 < niter) load_tile((it + 1) * 64);

        const int kb = it * 64 + wk * 32;       // this wave's 32-key subtile
        if (kb <= qrow + 15) {
            #pragma unroll
            for (int h = 0; h < 2; ++h) {
                f32x4 s = {};
                #pragma unroll
                for (int c = 0; c < 4; ++c) {
                    f16x8 fkh = *reinterpret_cast<const f16x8*>(&Khs[cur][wk * 32 + h * 16 + lo][c * 32 + hi * 8]);
                    f16x8 fkl = *reinterpret_cast<const f16x8*>(&Kls[cur][wk * 32 + h * 16 + lo][c * 32 + hi * 8]);
                    s = __builtin_amdgcn_mfma_f32_16x16x32_f16(qh[c], fkh, s, 0, 0, 0);
                    s = __builtin_amdgcn_mfma_f32_16x16x32_f16(qh[c], fkl, s, 0, 0, 0);
                    s = __builtin_amdgcn_mfma_f32_16x16x32_f16(ql[c], fkh, s, 0, 0, 0);
                }
                const int key = kb + h * 16 + lo;
                const int mk  = Ms[cur][wk * 32 + h * 16 + lo];
                #pragma unroll
                for (int r = 0; r < 4; ++r) {
                    const int q = qrow + hi * 4 + r;
                    float t = EXP2(s[r] * c2p);               // e^{2s} (inf ok)
                    float p = EXP2(c1 * fast_rcp(t + 1.0f));
                    p = (key <= q && mk != 0) ? p : 0.0f;     // causal + padding
                    rs[r] += p;
                    Plds[w][hi * 4 + r][h * 16 + lo] = f2bf(p);
                }
            }
            bf16x8 pa = *reinterpret_cast<const bf16x8*>(&Plds[w][lo][hi * 8]);
            #pragma unroll
            for (int dt = 0; dt < 8; ++dt) {
                bf16x8 vf = *reinterpret_cast<const bf16x8*>(&Vs[cur][dt * 16 + lo][wk * 32 + hi * 8]);
                acc[dt] = __builtin_amdgcn_mfma_f32_16x16x32_bf16(pa, vf, acc[dt], 0, 0, 0);
            }
        }

        if (it + 1 < niter) write_tile(cur ^ 1);
        __syncthreads();
    }

    // 2-way wk merge via LDS (reuses Khs region; last loop barrier separates)
    float* red = (float*)&Khs[0][0][0];
    if (wk == 1) {
        float* dst = red + ((size_t)wq * 64 + lane) * 36;
        #pragma unroll
        for (int dt = 0; dt < 8; ++dt)
            #pragma unroll
            for (int r = 0; r < 4; ++r) dst[dt * 4 + r] = acc[dt][r];
        #pragma unroll
        for (int r = 0; r < 4; ++r) dst[32 + r] = rs[r];
    }
    __syncthreads();
    if (wk == 0) {
        const float* src = red + ((size_t)wq * 64 + lane) * 36;
        #pragma unroll
        for (int dt = 0; dt < 8; ++dt)
            #pragma unroll
            for (int r = 0; r < 4; ++r) acc[dt][r] += src[dt * 4 + r];
        float inv[4];
        #pragma unroll
        for (int r = 0; r < 4; ++r) {
            float v = rs[r] + src[32 + r];
            v += __shfl_xor(v, 1);
            v += __shfl_xor(v, 2);
            v += __shfl_xor(v, 4);
            v += __shfl_xor(v, 8);
            inv[r] = fast_rcp(v);
        }
        #pragma unroll
        for (int dt = 0; dt < 8; ++dt)
            #pragma unroll
            for (int r = 0; r < 4; ++r) {
                const size_t q = (size_t)qrow + hi * 4 + r;
                out[((size_t)b * SEQ + q) * DHEAD + dt * 16 + lo] = acc[dt][r] * inv[r];
            }
    }
}

extern "C" void kernel_launch(void* const* d_in, const int* in_sizes, int n_in,
                              void* d_out, int out_size, void* d_ws, size_t ws_size,
                              hipStream_t stream) {
    const float* x   = (const float*)d_in[0];
    const int*   msk = (const int*)d_in[1];
    const float* WQ  = (const float*)d_in[2];
    const float* WK  = (const float*)d_in[3];
    const float* WV  = (const float*)d_in[4];
    float* out = (float*)d_out;

    // workspace: Qh|Ql|Kh|Kl (f16) | Vt (bf16), each B*L*128*2B = 4MB -> 20MB
    const size_t NE = (size_t)BATCH * SEQ * DHEAD;
    f16* Qh = (f16*)d_ws;
    f16* Ql = Qh + NE;
    f16* Kh = Ql + NE;
    f16* Kl = Kh + NE;
    unsigned short* Vtb = (unsigned short*)(Kl + NE);

    proj_kernel<<<dim3(BATCH * SEQ / 64), 512, 0, stream>>>(x, WQ, WK, WV, Qh, Ql, Kh, Kl, Vtb);
    attn_kernel<<<dim3(BATCH, SEQ / 64), 512, 0, stream>>>(Qh, Ql, Kh, Kl, Vtb, msk, out);
}